// Round 10
// baseline (204.599 us; speedup 1.0000x reference)
//
#include <hip/hip_runtime.h>
#include <hip/hip_bf16.h>
#include <stdint.h>

#define T_ 4
#define B_ 16
#define C_ 256
#define N_ 1024
#define HEADS_ 8
#define HD_ 32

typedef unsigned long long u64;
typedef unsigned char u8;

// ---------- prep: transpose the 4 weight matrices to [c][o] ----------
__global__ __launch_bounds__(256) void prep_transpose(
    const float* __restrict__ qw, const float* __restrict__ kw,
    const float* __restrict__ vw, const float* __restrict__ pw,
    float* __restrict__ wtq, float* __restrict__ wtk,
    float* __restrict__ wtv, float* __restrict__ wtp) {
  int c = blockIdx.x;
  int o = threadIdx.x;
  wtq[c * C_ + o] = qw[o * C_ + c];
  wtk[c * C_ + o] = kw[o * C_ + c];
  wtv[c * C_ + o] = vw[o * C_ + c];
  wtp[c * C_ + o] = pw[o * C_ + c];
}

// ---------- prep: BN scale/shift tables (verified) ----------
__global__ __launch_bounds__(256) void prep_bn(
    const float* __restrict__ qg, const float* __restrict__ qb2,
    const float* __restrict__ qmn, const float* __restrict__ qvr,
    const float* __restrict__ kg, const float* __restrict__ kb2,
    const float* __restrict__ kmn, const float* __restrict__ kvr,
    const float* __restrict__ vg, const float* __restrict__ vb2,
    const float* __restrict__ vmn, const float* __restrict__ vvr,
    const float* __restrict__ pg, const float* __restrict__ pb2,
    const float* __restrict__ pmn, const float* __restrict__ pvr,
    float* __restrict__ bnt) {
  int c = threadIdx.x;
  float rs;
  rs = sqrtf(qvr[c] + 1e-5f);
  bnt[0 * C_ + c] = qg[c] / rs;
  bnt[1 * C_ + c] = qb2[c] - qmn[c] * qg[c] / rs;
  rs = sqrtf(kvr[c] + 1e-5f);
  bnt[2 * C_ + c] = kg[c] / rs;
  bnt[3 * C_ + c] = kb2[c] - kmn[c] * kg[c] / rs;
  rs = sqrtf(vvr[c] + 1e-5f);
  bnt[4 * C_ + c] = vg[c] / rs;
  bnt[5 * C_ + c] = vb2[c] - vmn[c] * vg[c] / rs;
  rs = sqrtf(pvr[c] + 1e-5f);
  bnt[6 * C_ + c] = pg[c] / rs;
  bnt[7 * C_ + c] = pb2[c] - pmn[c] * pg[c] / rs;
}

// ---------- P0: shortcut LIF -> xs bitmasks [site][4 words], c = 64w + l ----
__global__ __launch_bounds__(256) void lif_shortcut(const float* __restrict__ x,
                                                    u64* __restrict__ xsm) {
  int b = blockIdx.x >> 5;          // 32 n-tiles of 32
  int n0 = (blockIdx.x & 31) << 5;
  int tid = threadIdx.x;
  int l = tid & 63, w = tid >> 6;
  __shared__ float tile[C_ * 33];
  float v[32];
#pragma unroll
  for (int i = 0; i < 32; i++) v[i] = 0.f;
  int c = (w << 6) + l;             // this thread's channel
  for (int t = 0; t < T_; t++) {
    __syncthreads();
    const float* xp = x + (((size_t)t * B_ + b) * C_) * N_ + n0;
    for (int idx = tid; idx < C_ * 32; idx += 256) {
      int cc = idx >> 5, nn = idx & 31;
      tile[cc * 33 + nn] = xp[(size_t)cc * N_ + nn];
    }
    __syncthreads();
#pragma unroll
    for (int nn = 0; nn < 32; nn++) {
      float xv = tile[c * 33 + nn];
      float h = v[nn] + (xv - v[nn]) * 0.5f;   // tau=2 exact halving
      bool s = h >= 1.0f;
      v[nn] = s ? 0.f : h;                     // hard reset, detach
      u64 bal = __ballot(s);
      if (l == nn) xsm[(((size_t)t * B_ + b) * N_ + n0 + nn) * 4 + w] = bal;
    }
  }
}

// ---------- P1 helper: one pass's chunked LDS-staged walk ----------
// acc[s][t][j] += sum over active channels of wt row, ascending c (bit-exact).
__device__ __forceinline__ void pass_walk(const float* __restrict__ wt,
                                          float* __restrict__ buf,
                                          const u64 (*msks)[4][4],
                                          float acc[8][4][4],
                                          int tid, int l, int wv) {
#pragma unroll
  for (int s = 0; s < 8; s++)
#pragma unroll
    for (int t = 0; t < 4; t++)
#pragma unroll
      for (int j = 0; j < 4; j++) acc[s][t][j] = 0.f;
  for (int wd = 0; wd < 4; wd++) {
    __syncthreads();                 // prior walk done; safe to overwrite buf
#pragma unroll
    for (int i = 0; i < 16; i++) {
      int idx = (i << 8) + tid;      // 4096 float4 = 64 KB
      ((float4*)buf)[idx] = ((const float4*)(wt + ((size_t)wd << 14)))[idx];
    }
    __syncthreads();
#pragma unroll
    for (int s = 0; s < 8; s++) {
      int ls = (wv << 3) + s;
#pragma unroll
      for (int t = 0; t < 4; t++) {
        u64 m = msks[ls][t][wd];
        while (m) {
          int c0 = __builtin_ctzll(m); m &= m - 1;
          int c1 = 64, c2 = 64, c3 = 64;     // 64 = zero row (+0.0 exact)
          if (m) { c1 = __builtin_ctzll(m); m &= m - 1; }
          if (m) { c2 = __builtin_ctzll(m); m &= m - 1; }
          if (m) { c3 = __builtin_ctzll(m); m &= m - 1; }
          const float* p0 = buf + (c0 << 8) + l;
          const float* p1 = buf + (c1 << 8) + l;
          const float* p2 = buf + (c2 << 8) + l;
          const float* p3 = buf + (c3 << 8) + l;
          float r00 = p0[0], r01 = p0[64], r02 = p0[128], r03 = p0[192];
          float r10 = p1[0], r11 = p1[64], r12 = p1[128], r13 = p1[192];
          float r20 = p2[0], r21 = p2[64], r22 = p2[128], r23 = p2[192];
          float r30 = p3[0], r31 = p3[64], r32 = p3[128], r33 = p3[192];
          acc[s][t][0] += r00; acc[s][t][0] += r10;
          acc[s][t][0] += r20; acc[s][t][0] += r30;
          acc[s][t][1] += r01; acc[s][t][1] += r11;
          acc[s][t][1] += r21; acc[s][t][1] += r31;
          acc[s][t][2] += r02; acc[s][t][2] += r12;
          acc[s][t][2] += r22; acc[s][t][2] += r32;
          acc[s][t][3] += r03; acc[s][t][3] += r13;
          acc[s][t][3] += r23; acc[s][t][3] += r33;
        }
      }
    }
  }
}

// ---------- P1: LDS-staged sparse q/k/v conv + BN + LIF ----------
// grid = b(16) x nt(32 tiles of 32 n); wave wv owns sites ls = 8wv..8wv+7.
// lane l owns out-channels o = 64j + l (r9 convention, all consumers match).
__global__ __launch_bounds__(256, 2) void qkv_lds(
    const u64* __restrict__ xsm,
    const float* __restrict__ wtq, const float* __restrict__ wtk,
    const float* __restrict__ wtv, const float* __restrict__ bnt,
    float* __restrict__ pkv, u64* __restrict__ qm_out,
    float* __restrict__ vout) {
  int b = blockIdx.x >> 5;
  int nt = blockIdx.x & 31;
  int n0 = nt << 5;
  int tid = threadIdx.x;
  int l = tid & 63, wv = tid >> 6;

  __shared__ float buf[65 * 256];   // 66.5 KB: 64-row chunk + zero row
  __shared__ u64 msks[32][4][4];    // 4 KB  [ls][t][wd]
  __shared__ u64 kball[32][4][4];   // 4 KB  [ls][t][j] k-spike ballots

  // zero row + mask preload
  buf[64 * 256 + tid] = 0.f;
#pragma unroll
  for (int r = 0; r < 2; r++) {
    int idx = (r << 8) + tid;
    int ls = idx >> 4, t = (idx >> 2) & 3, wd = idx & 3;
    msks[ls][t][wd] =
        xsm[((((size_t)t * B_ + b) * N_ + n0 + ls) << 2) + wd];
  }

  float acc[8][4][4];

  // ================= Q pass =================
  pass_walk(wtq, buf, msks, acc, tid, l, wv);
  {
    float sc[4], sh[4];
#pragma unroll
    for (int j = 0; j < 4; j++) {
      sc[j] = bnt[0 * C_ + (j << 6) + l];
      sh[j] = bnt[1 * C_ + (j << 6) + l];
    }
#pragma unroll
    for (int s = 0; s < 8; s++) {
      int n = n0 + (wv << 3) + s;
#pragma unroll
      for (int j = 0; j < 4; j++) {
        float vq = 0.f;
#pragma unroll
        for (int t = 0; t < 4; t++) {
          float p = acc[s][t][j] * sc[j] + sh[j];
          float h = vq + (p - vq) * 0.5f;
          bool sq = h >= 1.0f;
          vq = sq ? 0.f : h;
          u64 bq = __ballot(sq);
          if (l == (t << 2) + j)
            qm_out[((((size_t)t * B_ + b) * N_ + n) << 2) + j] = bq;
        }
      }
    }
  }

  // ================= K pass =================
  pass_walk(wtk, buf, msks, acc, tid, l, wv);
  {
    float sc[4], sh[4];
#pragma unroll
    for (int j = 0; j < 4; j++) {
      sc[j] = bnt[2 * C_ + (j << 6) + l];
      sh[j] = bnt[3 * C_ + (j << 6) + l];
    }
#pragma unroll
    for (int s = 0; s < 8; s++) {
      int ls = (wv << 3) + s;
#pragma unroll
      for (int j = 0; j < 4; j++) {
        float vk = 0.f;
#pragma unroll
        for (int t = 0; t < 4; t++) {
          float p = acc[s][t][j] * sc[j] + sh[j];
          float h = vk + (p - vk) * 0.5f;
          bool sk = h >= 1.0f;
          vk = sk ? 0.f : h;
          u64 bk = __ballot(sk);
          if (l == (t << 2) + j) kball[ls][t][j] = bk;
        }
      }
    }
  }

  // ================= V pass =================
  pass_walk(wtv, buf, msks, acc, tid, l, wv);
  int cnt[4][4];
#pragma unroll
  for (int t = 0; t < 4; t++)
#pragma unroll
    for (int j = 0; j < 4; j++) cnt[t][j] = 0;
  {
    float sc[4], sh[4];
#pragma unroll
    for (int j = 0; j < 4; j++) {
      sc[j] = bnt[4 * C_ + (j << 6) + l];
      sh[j] = bnt[5 * C_ + (j << 6) + l];
    }
#pragma unroll
    for (int s = 0; s < 8; s++) {
      int ls = (wv << 3) + s;
      int n = n0 + ls;
#pragma unroll
      for (int j = 0; j < 4; j++) {
        int o = (j << 6) + l;
        float vv = 0.f;
#pragma unroll
        for (int t = 0; t < 4; t++) {
          float p = acc[s][t][j] * sc[j] + sh[j];
          float h = vv + (p - vv) * 0.5f;
          bool sv = h >= 1.0f;
          vv = sv ? 0.f : h;
          vout[(((size_t)t * B_ + b) * HEADS_ + (o >> 5)) * ((size_t)N_ * HD_) +
               (size_t)n * HD_ + (o & 31)] = sv ? 1.0f : 0.0f;
          cnt[t][j] += (((kball[ls][t][j] >> l) & 1ull) && sv) ? 1 : 0;
        }
      }
    }
  }

  // scnt reduction overlaid on buf (all walks complete)
  __syncthreads();
  int* scnt = (int*)buf;            // [wv][t][c] = 4*4*256 ints = 16 KB
#pragma unroll
  for (int t = 0; t < 4; t++)
#pragma unroll
    for (int j = 0; j < 4; j++)
      scnt[((wv << 2) + t) * C_ + (j << 6) + l] = cnt[t][j];
  __syncthreads();
  for (int idx = tid; idx < 4 * C_; idx += 256) {
    int t = idx >> 8, c = idx & 255;
    int s = scnt[(0 + t) * C_ + c] + scnt[(4 + t) * C_ + c] +
            scnt[(8 + t) * C_ + c] + scnt[(12 + t) * C_ + c];
    pkv[(((size_t)t * B_ + b) * 32 + nt) * C_ + c] = (float)s;
  }
}

// ---------- P2: reduce kv partials + talking-heads LIF (v_th=0.5) ----------
// thread c; wave j = c>>6, lane l = c&63; ballot word j, bit l <-> c = 64j+l.
__global__ __launch_bounds__(256) void kv_lif_kernel(const float* __restrict__ pkv,
                                                     u64* __restrict__ kvsm) {
  int b = blockIdx.x;
  int c = threadIdx.x;
  int l = c & 63, j = c >> 6;
  float v = 0.f;
  for (int t = 0; t < 4; t++) {
    const float* p = pkv + (((size_t)t * B_ + b) * 32) * C_ + c;
    float kv = 0.f;
#pragma unroll
    for (int i = 0; i < 32; i++) kv += p[(size_t)i * C_];  // exact ints
    float h = v + (kv - v) * 0.5f;
    bool s = h >= 0.5f;
    v = s ? 0.f : h;
    u64 bal = __ballot(s);
    if (l == t) kvsm[((size_t)t * B_ + b) * 4 + j] = bal;
  }
}

// ---------- P3: attn = q & kvs -> sparse proj + bias + BN + identity ----------
__global__ __launch_bounds__(256) void proj_sparse(
    const u64* __restrict__ qm, const u64* __restrict__ kvsm,
    const float* __restrict__ wtp, const float* __restrict__ bnt,
    const float* __restrict__ pbias, const float* __restrict__ x,
    float* __restrict__ out) {
  int tb = blockIdx.x >> 5;         // 64 (t,b) x 32 n-tiles of 32
  int n0 = (blockIdx.x & 31) << 5;
  int t = tb >> 4, b = tb & 15;
  int tid = threadIdx.x;
  int l = tid & 63, w = tid >> 6;
  __shared__ float tile[C_ * 33];
  u64 kvm[4];
#pragma unroll
  for (int wd = 0; wd < 4; wd++) kvm[wd] = kvsm[((size_t)t * B_ + b) * 4 + wd];
  for (int nn = w; nn < 32; nn += 4) {
    int n = n0 + nn;
    float acc[4] = {0.f, 0.f, 0.f, 0.f};
    const u64* mp = qm + ((((size_t)t * B_ + b) * N_ + n) << 2);
#pragma unroll
    for (int wd = 0; wd < 4; wd++) {
      u64 m = mp[wd] & kvm[wd];
      while (m) {
        int c = (wd << 6) + __builtin_ctzll(m);
        m &= (m - 1);
        const float* rp = wtp + c * C_;
#pragma unroll
        for (int j = 0; j < 4; j++) acc[j] += rp[(j << 6) + l];
      }
    }
#pragma unroll
    for (int j = 0; j < 4; j++) tile[((j << 6) + l) * 33 + nn] = acc[j];
  }
  __syncthreads();
  // per-row epilogue, coalesced over n (verified math)
  int col = l & 31;
  int half = l >> 5;
  for (int r = (w << 1) + half; r < C_; r += 8) {
    float val = tile[r * 33 + col];
    float z = (val + pbias[r]) * bnt[6 * C_ + r] + bnt[7 * C_ + r];
    size_t xi = (((size_t)t * B_ + b) * C_ + r) * N_ + n0 + col;
    out[xi] = z + x[xi];
  }
}

// ---------- diagnostic: if ws too small, zero the output ----------
__global__ __launch_bounds__(256) void fill_zero_f32(float* p, size_t n) {
  size_t i = (size_t)blockIdx.x * 256 + threadIdx.x;
  if (i < n) p[i] = 0.0f;
}

extern "C" void kernel_launch(void* const* d_in, const int* in_sizes, int n_in,
                              void* d_out, int out_size, void* d_ws, size_t ws_size,
                              hipStream_t stream) {
  const float* x  = (const float*)d_in[0];
  const float* qw = (const float*)d_in[1];
  const float* qg = (const float*)d_in[2];
  const float* qb = (const float*)d_in[3];
  const float* qm = (const float*)d_in[4];
  const float* qv = (const float*)d_in[5];
  const float* kw = (const float*)d_in[6];
  const float* kg = (const float*)d_in[7];
  const float* kb = (const float*)d_in[8];
  const float* km = (const float*)d_in[9];
  const float* kv = (const float*)d_in[10];
  const float* vw = (const float*)d_in[11];
  const float* vg = (const float*)d_in[12];
  const float* vb2 = (const float*)d_in[13];
  const float* vm = (const float*)d_in[14];
  const float* vv = (const float*)d_in[15];
  const float* pw = (const float*)d_in[16];
  const float* pbias = (const float*)d_in[17];
  const float* pg = (const float*)d_in[18];
  const float* pb = (const float*)d_in[19];
  const float* pm = (const float*)d_in[20];
  const float* pv = (const float*)d_in[21];

  const size_t needed = 7350272ull;   // ~7.35 MB (ws proven >= 43 MB in r2)
  if (ws_size < needed) {
    size_t n = (size_t)out_size;
    fill_zero_f32<<<(unsigned)((n + 255) / 256), 256, 0, stream>>>(
        (float*)d_out, n);
    return;
  }

  char* ws = (char*)d_ws;
  float* wtq = (float*)(ws + 0);         // 256 KB [c][o]
  float* wtk = (float*)(ws + 262144);    // 256 KB
  float* wtv = (float*)(ws + 524288);    // 256 KB
  float* wtp = (float*)(ws + 786432);    // 256 KB
  float* bnt = (float*)(ws + 1048576);   // 8 KB
  u64*   xsm = (u64*)  (ws + 1056768);   // 2 MB  [site][4 words], c = 64w+l
  u64*   qmm = (u64*)  (ws + 3153920);   // 2 MB  [site][4 words], c = 64j+l
  float* pkv = (float*)(ws + 5251072);   // 2 MB  [t][b][nt(32)][c]
  u64*   kvsm = (u64*) (ws + 7348224);   // 2 KB  [t][b][4 words]

  float* out  = (float*)d_out;
  float* vout = out + (size_t)T_ * B_ * C_ * N_;

  prep_transpose<<<256, 256, 0, stream>>>(qw, kw, vw, pw, wtq, wtk, wtv, wtp);
  prep_bn<<<1, 256, 0, stream>>>(qg, qb, qm, qv, kg, kb, km, kv,
                                 vg, vb2, vm, vv, pg, pb, pm, pv, bnt);
  lif_shortcut<<<512, 256, 0, stream>>>(x, xsm);
  qkv_lds<<<512, 256, 0, stream>>>(xsm, wtq, wtk, wtv, bnt, pkv, qmm, vout);
  kv_lif_kernel<<<16, 256, 0, stream>>>(pkv, kvsm);
  proj_sparse<<<2048, 256, 0, stream>>>(qmm, kvsm, wtp, bnt, pbias, x, out);
}

// Round 11
// 187.455 us; speedup vs baseline: 1.0915x; 1.0915x over previous
//
#include <hip/hip_runtime.h>
#include <hip/hip_bf16.h>
#include <stdint.h>

#define T_ 4
#define B_ 16
#define C_ 256
#define N_ 1024
#define HEADS_ 8
#define HD_ 32
#define ZROW 256          // zero row index in wqkv

typedef unsigned long long u64;
typedef unsigned char u8;

__device__ __forceinline__ u64 rf64(u64 v) {
  unsigned lo = __builtin_amdgcn_readfirstlane((unsigned)v);
  unsigned hi = __builtin_amdgcn_readfirstlane((unsigned)(v >> 32));
  return ((u64)hi << 32) | (u64)lo;
}

// ---------- prep: wqkv[257][768] (row 256 = zeros), wtp[c][256], BN ----------
__global__ __launch_bounds__(256) void prep_kernel(
    const float* __restrict__ qw, const float* __restrict__ kw,
    const float* __restrict__ vw, const float* __restrict__ pw,
    const float* __restrict__ qg, const float* __restrict__ qb2,
    const float* __restrict__ qmn, const float* __restrict__ qvr,
    const float* __restrict__ kg, const float* __restrict__ kb2,
    const float* __restrict__ kmn, const float* __restrict__ kvr,
    const float* __restrict__ vg, const float* __restrict__ vb2,
    const float* __restrict__ vmn, const float* __restrict__ vvr,
    const float* __restrict__ pg, const float* __restrict__ pb2,
    const float* __restrict__ pmn, const float* __restrict__ pvr,
    float* __restrict__ wqkv, float* __restrict__ wtp,
    float* __restrict__ bnt) {
  if (blockIdx.x < 256) {
    int c = blockIdx.x;
    int o = threadIdx.x;
    wqkv[c * 768 + o]       = qw[o * C_ + c];
    wqkv[c * 768 + 256 + o] = kw[o * C_ + c];
    wqkv[c * 768 + 512 + o] = vw[o * C_ + c];
    wtp[c * C_ + o]         = pw[o * C_ + c];
  } else if (blockIdx.x == 256) {
    int c = threadIdx.x;
    float rs;
    rs = sqrtf(qvr[c] + 1e-5f);
    bnt[0 * C_ + c] = qg[c] / rs;
    bnt[1 * C_ + c] = qb2[c] - qmn[c] * qg[c] / rs;
    rs = sqrtf(kvr[c] + 1e-5f);
    bnt[2 * C_ + c] = kg[c] / rs;
    bnt[3 * C_ + c] = kb2[c] - kmn[c] * kg[c] / rs;
    rs = sqrtf(vvr[c] + 1e-5f);
    bnt[4 * C_ + c] = vg[c] / rs;
    bnt[5 * C_ + c] = vb2[c] - vmn[c] * vg[c] / rs;
    rs = sqrtf(pvr[c] + 1e-5f);
    bnt[6 * C_ + c] = pg[c] / rs;
    bnt[7 * C_ + c] = pb2[c] - pmn[c] * pg[c] / rs;
  } else {
    int o = threadIdx.x;           // zero row
    wqkv[ZROW * 768 + o]       = 0.f;
    wqkv[ZROW * 768 + 256 + o] = 0.f;
    wqkv[ZROW * 768 + 512 + o] = 0.f;
  }
}

// ---------- P0: shortcut LIF -> xs bitmasks [site][4 words], c = 64wd + bit --
__global__ __launch_bounds__(256) void lif_shortcut(const float* __restrict__ x,
                                                    u64* __restrict__ xsm) {
  int b = blockIdx.x >> 5;          // 32 n-tiles of 32
  int n0 = (blockIdx.x & 31) << 5;
  int tid = threadIdx.x;
  int l = tid & 63, w = tid >> 6;
  __shared__ float tile[C_ * 33];
  float v[32];
#pragma unroll
  for (int i = 0; i < 32; i++) v[i] = 0.f;
  int c = (w << 6) + l;             // this thread's channel
  for (int t = 0; t < T_; t++) {
    __syncthreads();
    const float* xp = x + (((size_t)t * B_ + b) * C_) * N_ + n0;
    for (int idx = tid; idx < C_ * 32; idx += 256) {
      int cc = idx >> 5, nn = idx & 31;
      tile[cc * 33 + nn] = xp[(size_t)cc * N_ + nn];
    }
    __syncthreads();
#pragma unroll
    for (int nn = 0; nn < 32; nn++) {
      float xv = tile[c * 33 + nn];
      float h = v[nn] + (xv - v[nn]) * 0.5f;   // tau=2 exact halving
      bool s = h >= 1.0f;
      v[nn] = s ? 0.f : h;                     // hard reset, detach
      u64 bal = __ballot(s);
      if (l == nn) xsm[(((size_t)t * B_ + b) * N_ + n0 + nn) * 4 + w] = bal;
    }
  }
}

#define ACC3(tt, Q, K, V)                                              \
  aq[tt][0] += Q.x; aq[tt][1] += Q.y; aq[tt][2] += Q.z; aq[tt][3] += Q.w; \
  ak[tt][0] += K.x; ak[tt][1] += K.y; ak[tt][2] += K.z; ak[tt][3] += K.w; \
  av[tt][0] += V.x; av[tt][1] += V.y; av[tt][2] += V.z; av[tt][3] += V.w;

// ---------- P1: sparse q/k/v conv + BN + LIF (merged 4-t walk, float4) -------
// grid = b(16) x nt(128 tiles of 8 n); wave wv owns sites nn = wv, wv+4.
// lane l owns out-channels o = 4l+j; ballot word j, bit l <-> c = 4l+j.
__global__ __launch_bounds__(256) void qkv_sparse(
    const u64* __restrict__ xsm, const float* __restrict__ wqkv,
    const float* __restrict__ bnt, float* __restrict__ pkv,
    u64* __restrict__ qm_out, float* __restrict__ vout) {
  int b = blockIdx.x >> 7;
  int nt = blockIdx.x & 127;
  int n0 = nt << 3;
  int tid = threadIdx.x;
  int l = tid & 63, wv = tid >> 6;

  float qsc[4], qsh[4], ksc[4], ksh[4], vsc[4], vsh[4];
#pragma unroll
  for (int j = 0; j < 4; j++) {
    int o = (l << 2) + j;
    qsc[j] = bnt[0 * C_ + o]; qsh[j] = bnt[1 * C_ + o];
    ksc[j] = bnt[2 * C_ + o]; ksh[j] = bnt[3 * C_ + o];
    vsc[j] = bnt[4 * C_ + o]; vsh[j] = bnt[5 * C_ + o];
  }
  int cnt[4][4];
#pragma unroll
  for (int t = 0; t < 4; t++)
#pragma unroll
    for (int j = 0; j < 4; j++) cnt[t][j] = 0;

  for (int nn = wv; nn < 8; nn += 4) {
    int n = n0 + nn;
    float aq[4][4], ak[4][4], av[4][4];   // [t][j]
#pragma unroll
    for (int t = 0; t < 4; t++)
#pragma unroll
      for (int j = 0; j < 4; j++) { aq[t][j] = 0.f; ak[t][j] = 0.f; av[t][j] = 0.f; }
    // preload the 16 mask words into SGPRs (wave-uniform)
    u64 msk[4][4];
#pragma unroll
    for (int t = 0; t < 4; t++)
#pragma unroll
      for (int wd = 0; wd < 4; wd++)
        msk[t][wd] = rf64(xsm[((((size_t)t * B_ + b) * N_ + n) << 2) + wd]);
    // merged walk: 4 independent t-chains, word-by-word, ascending c per t
#pragma unroll
    for (int wd = 0; wd < 4; wd++) {
      u64 m0 = msk[0][wd], m1 = msk[1][wd], m2 = msk[2][wd], m3 = msk[3][wd];
      while (m0 | m1 | m2 | m3) {
        int c0 = ZROW, c1 = ZROW, c2 = ZROW, c3 = ZROW;
        if (m0) { c0 = (wd << 6) + __builtin_ctzll(m0); m0 &= m0 - 1; }
        if (m1) { c1 = (wd << 6) + __builtin_ctzll(m1); m1 &= m1 - 1; }
        if (m2) { c2 = (wd << 6) + __builtin_ctzll(m2); m2 &= m2 - 1; }
        if (m3) { c3 = (wd << 6) + __builtin_ctzll(m3); m3 &= m3 - 1; }
        const float4* p0 = (const float4*)(wqkv + c0 * 768) + l;
        const float4* p1 = (const float4*)(wqkv + c1 * 768) + l;
        const float4* p2 = (const float4*)(wqkv + c2 * 768) + l;
        const float4* p3 = (const float4*)(wqkv + c3 * 768) + l;
        float4 q0 = p0[0], k0 = p0[64], v0 = p0[128];
        float4 q1 = p1[0], k1 = p1[64], v1 = p1[128];
        float4 q2 = p2[0], k2 = p2[64], v2 = p2[128];
        float4 q3 = p3[0], k3 = p3[64], v3 = p3[128];
        ACC3(0, q0, k0, v0)
        ACC3(1, q1, k1, v1)
        ACC3(2, q2, k2, v2)
        ACC3(3, q3, k3, v3)
      }
    }
    // BN + LIF scan: t outer, j inner (r6-verified structure)
    float vq[4] = {0.f, 0.f, 0.f, 0.f};
    float vk[4] = {0.f, 0.f, 0.f, 0.f};
    float vv2[4] = {0.f, 0.f, 0.f, 0.f};
#pragma unroll
    for (int t = 0; t < 4; t++) {
      size_t site = ((size_t)t * B_ + b) * N_ + n;
      float vo[4];
#pragma unroll
      for (int j = 0; j < 4; j++) {
        float pq = aq[t][j] * qsc[j] + qsh[j];
        float pk = ak[t][j] * ksc[j] + ksh[j];
        float pv = av[t][j] * vsc[j] + vsh[j];
        float hq = vq[j] + (pq - vq[j]) * 0.5f;
        float hk = vk[j] + (pk - vk[j]) * 0.5f;
        float hv = vv2[j] + (pv - vv2[j]) * 0.5f;
        bool sq = hq >= 1.0f; vq[j] = sq ? 0.f : hq;
        bool sk = hk >= 1.0f; vk[j] = sk ? 0.f : hk;
        bool sv = hv >= 1.0f; vv2[j] = sv ? 0.f : hv;
        vo[j] = sv ? 1.0f : 0.0f;
        cnt[t][j] += (sk && sv) ? 1 : 0;
        u64 bq = __ballot(sq);
        if (l == (t << 2) + j) qm_out[(site << 2) + j] = bq;
      }
      // contiguous float4 vout store: head = l>>3, hd base = (l&7)*4
      float* vp = vout +
          ((((size_t)t * B_ + b) * HEADS_ + (l >> 3)) * (size_t)N_ + n) * HD_ +
          ((l & 7) << 2);
      float4 o4; o4.x = vo[0]; o4.y = vo[1]; o4.z = vo[2]; o4.w = vo[3];
      *(float4*)vp = o4;
    }
  }
  // cross-wave reduction of kv partial counts (deterministic, no atomics)
  __shared__ int scnt[4][4][C_];
#pragma unroll
  for (int t = 0; t < 4; t++)
#pragma unroll
    for (int j = 0; j < 4; j++) scnt[wv][t][(l << 2) + j] = cnt[t][j];
  __syncthreads();
  // coalesced pkv write: layout [t][b][nt(128)][c]
  for (int idx = tid; idx < 4 * C_; idx += 256) {
    int t = idx >> 8, c = idx & 255;
    int s = scnt[0][t][c] + scnt[1][t][c] + scnt[2][t][c] + scnt[3][t][c];
    pkv[(((size_t)t * B_ + b) * 128 + nt) * C_ + c] = (float)s;
  }
}

// ---------- P2: reduce kv partials + talking-heads LIF (v_th=0.5) ----------
// thread tid -> channel c = 4l+j (l=tid&63, j=tid>>6); ballot word matches qm.
__global__ __launch_bounds__(256) void kv_lif_kernel(const float* __restrict__ pkv,
                                                     u64* __restrict__ kvsm) {
  int b = blockIdx.x;
  int tid = threadIdx.x;
  int l = tid & 63, j = tid >> 6;
  int c = (l << 2) + j;
  float v = 0.f;
  for (int t = 0; t < 4; t++) {
    const float* p = pkv + (((size_t)t * B_ + b) * 128) * C_ + c;
    float kv = 0.f;
#pragma unroll
    for (int i = 0; i < 128; i++) kv += p[(size_t)i * C_];  // exact ints
    float h = v + (kv - v) * 0.5f;
    bool s = h >= 0.5f;
    v = s ? 0.f : h;
    u64 bal = __ballot(s);
    if (l == t) kvsm[((size_t)t * B_ + b) * 4 + j] = bal;
  }
}

// ---------- P3: attn = q & kvs -> sparse proj + bias + BN + identity ----------
// qm/kvs word j, bit li <-> c = 4li + j (r6-verified decode).
__global__ __launch_bounds__(256) void proj_sparse(
    const u64* __restrict__ qm, const u64* __restrict__ kvsm,
    const float* __restrict__ wtp, const float* __restrict__ bnt,
    const float* __restrict__ pbias, const float* __restrict__ x,
    float* __restrict__ out) {
  int tb = blockIdx.x >> 5;         // 64 (t,b) x 32 n-tiles of 32
  int n0 = (blockIdx.x & 31) << 5;
  int t = tb >> 4, b = tb & 15;
  int tid = threadIdx.x;
  int l = tid & 63, w = tid >> 6;
  __shared__ float tile[C_ * 33];
  u64 kvm[4];
#pragma unroll
  for (int j = 0; j < 4; j++) kvm[j] = kvsm[((size_t)t * B_ + b) * 4 + j];
  for (int nn = w; nn < 32; nn += 4) {
    int n = n0 + nn;
    float acc[4] = {0.f, 0.f, 0.f, 0.f};
    size_t site = ((size_t)t * B_ + b) * N_ + n;
    const u64* mp = qm + (site << 2);
#pragma unroll
    for (int j = 0; j < 4; j++) {
      u64 m = rf64(mp[j]) & kvm[j];
      while (m) {
        int li = __builtin_ctzll(m);
        m &= m - 1;
        int c = (li << 2) + j;      // c = 4*bit + j layout
        const float* rp = wtp + c * C_;
#pragma unroll
        for (int jj = 0; jj < 4; jj++) acc[jj] += rp[(jj << 6) + l];
      }
    }
#pragma unroll
    for (int jj = 0; jj < 4; jj++) tile[((jj << 6) + l) * 33 + nn] = acc[jj];
  }
  __syncthreads();
  // per-row epilogue, coalesced over n (verified math)
  int col = l & 31;
  int half = l >> 5;
  for (int r = (w << 1) + half; r < C_; r += 8) {
    float val = tile[r * 33 + col];
    float z = (val + pbias[r]) * bnt[6 * C_ + r] + bnt[7 * C_ + r];
    size_t xi = (((size_t)t * B_ + b) * C_ + r) * N_ + n0 + col;
    out[xi] = z + x[xi];
  }
}

// ---------- diagnostic: if ws too small, zero the output ----------
__global__ __launch_bounds__(256) void fill_zero_f32(float* p, size_t n) {
  size_t i = (size_t)blockIdx.x * 256 + threadIdx.x;
  if (i < n) p[i] = 0.0f;
}

extern "C" void kernel_launch(void* const* d_in, const int* in_sizes, int n_in,
                              void* d_out, int out_size, void* d_ws, size_t ws_size,
                              hipStream_t stream) {
  const float* x  = (const float*)d_in[0];
  const float* qw = (const float*)d_in[1];
  const float* qg = (const float*)d_in[2];
  const float* qb = (const float*)d_in[3];
  const float* qm = (const float*)d_in[4];
  const float* qv = (const float*)d_in[5];
  const float* kw = (const float*)d_in[6];
  const float* kg = (const float*)d_in[7];
  const float* kb = (const float*)d_in[8];
  const float* km = (const float*)d_in[9];
  const float* kv = (const float*)d_in[10];
  const float* vw = (const float*)d_in[11];
  const float* vg = (const float*)d_in[12];
  const float* vb2 = (const float*)d_in[13];
  const float* vm = (const float*)d_in[14];
  const float* vv = (const float*)d_in[15];
  const float* pw = (const float*)d_in[16];
  const float* pbias = (const float*)d_in[17];
  const float* pg = (const float*)d_in[18];
  const float* pb = (const float*)d_in[19];
  const float* pm = (const float*)d_in[20];
  const float* pv = (const float*)d_in[21];

  const size_t needed = 13644800ull;   // ~13.6 MB (ws proven >= 43 MB in r2)
  if (ws_size < needed) {
    size_t n = (size_t)out_size;
    fill_zero_f32<<<(unsigned)((n + 255) / 256), 256, 0, stream>>>(
        (float*)d_out, n);
    return;
  }

  char* ws = (char*)d_ws;
  float* wqkv = (float*)(ws + 0);         // 790 KB [257][768], row 256 = 0
  float* wtp  = (float*)(ws + 789504);    // 256 KB [c][o]
  float* bnt  = (float*)(ws + 1051648);   // 8 KB
  u64*   xsm  = (u64*)  (ws + 1059840);   // 2 MB  [site][4 words], c = 64wd+bit
  u64*   qmm  = (u64*)  (ws + 3156992);   // 2 MB  [site][4 j-words], c = 4l+j
  float* pkv  = (float*)(ws + 5254144);   // 8 MB  [t][b][nt(128)][c]
  u64*   kvsm = (u64*)  (ws + 13642752);  // 2 KB  [t][b][4 j-words]

  float* out  = (float*)d_out;
  float* vout = out + (size_t)T_ * B_ * C_ * N_;

  prep_kernel<<<258, 256, 0, stream>>>(qw, kw, vw, pw,
                                       qg, qb, qm, qv, kg, kb, km, kv,
                                       vg, vb2, vm, vv, pg, pb, pm, pv,
                                       wqkv, wtp, bnt);
  lif_shortcut<<<512, 256, 0, stream>>>(x, xsm);
  qkv_sparse<<<2048, 256, 0, stream>>>(xsm, wqkv, bnt, pkv, qmm, vout);
  kv_lif_kernel<<<16, 256, 0, stream>>>(pkv, kvsm);
  proj_sparse<<<2048, 256, 0, stream>>>(qmm, kvsm, wtp, bnt, pbias, x, out);
}